// Round 4
// baseline (512.132 us; speedup 1.0000x reference)
//
#include <hip/hip_runtime.h>

typedef __bf16 bf16;
typedef __attribute__((ext_vector_type(8))) __bf16 bf16x8;
typedef __attribute__((ext_vector_type(4))) __bf16 bf16x4;
typedef __attribute__((ext_vector_type(4))) float f32x4;

#define B_  32
#define S_  2048
#define DC  1024
#define DQ  1024
#define H_  512
#define M_  (B_*S_)

#define BM  64             // rows per block
#define BN  512            // full H per block -> ctx fetched exactly once
#define BK  32

// async global->LDS, 16B per lane
#define GLD16(g, l) __builtin_amdgcn_global_load_lds( \
    (__attribute__((address_space(1))) void*)(g),     \
    (__attribute__((address_space(3))) void*)(l), 16, 0, 0)

// ---------- Prep: blocks 0..255 = Wc->bf16 transpose tiles; 256..511 = qb GEMV ----------
__global__ __launch_bounds__(256) void k_prep(const float* __restrict__ W1,
                                              const float* __restrict__ query,
                                              const float* __restrict__ b1,
                                              bf16* __restrict__ WcT2,
                                              float* __restrict__ qb) {
    const int bid = blockIdx.x, tid = threadIdx.x;
    if (bid < 256) {
        // W1[:1024] (k-major) -> WcT2 [kb(32)][col(512)][kk(32)] bf16
        __shared__ bf16 t[32 * 68];            // [kk][h-in-tile], pad 4
        const int kb = bid >> 3;               // 0..31
        const int cb = bid & 7;                // 0..7, 64-col tile
        #pragma unroll
        for (int i = 0; i < 2; ++i) {
            int idx = i * 256 + tid;           // 0..511
            int k  = idx >> 4;                 // 0..31
            int h4 = (idx & 15) * 4;           // 0..60
            const float4 v = *(const float4*)(W1 + ((size_t)(kb * 32 + k)) * H_ + cb * 64 + h4);
            bf16x4 pk = { (bf16)v.x, (bf16)v.y, (bf16)v.z, (bf16)v.w };
            *(bf16x4*)(&t[k * 68 + h4]) = pk;
        }
        __syncthreads();
        const int col = tid >> 2;              // 0..63
        const int kk0 = (tid & 3) * 8;         // 0,8,16,24
        bf16x8 o;
        #pragma unroll
        for (int j = 0; j < 8; ++j) o[j] = t[(kk0 + j) * 68 + col];
        *(bf16x8*)(WcT2 + (size_t)kb * 16384 + (size_t)(cb * 64 + col) * 32 + kk0) = o;
    } else {
        // qb[b][h] = query[b,:] . Wq[:,h] + b1[h]
        const int r = bid - 256;
        const int hblk = r & 7;                // 0..7
        const int b    = r >> 3;               // 0..31
        __shared__ float q[DQ];
        __shared__ float red[256];
        #pragma unroll
        for (int i = 0; i < 4; ++i)
            q[tid + i * 256] = query[(size_t)b * DQ + tid + i * 256];
        __syncthreads();
        const int h  = hblk * 64 + (tid & 63);
        const int kc = tid >> 6;               // 0..3
        const float* w = W1 + (size_t)DC * H_ + (size_t)(kc * 256) * H_ + h;
        const float* qv = q + kc * 256;
        float acc = 0.0f;
        #pragma unroll 8
        for (int k = 0; k < 256; ++k)
            acc = fmaf(qv[k], w[(size_t)k * H_], acc);
        red[tid] = acc;
        __syncthreads();
        if (tid < 64)
            qb[(size_t)b * H_ + hblk * 64 + tid] =
                red[tid] + red[tid + 64] + red[tid + 128] + red[tid + 192] + b1[hblk * 64 + tid];
    }
}

// ---------- Kernel G: score[row] = sum_h tanh(ctx@Wc + qb)[h]*w2[h] ----------
// 1024 blocks x 256 thr = 4 waves (1m x 4n), wave tile 64x128, BK=32.
// 72 KB LDS + ~210 regs/wave -> 2 blocks/CU = 2 independent barrier domains
// that overlap each other's vmcnt drain (the m97/m114 mechanism).
// Optionally stores the converted bf16 A tiles to ctxb (each elem staged once).
template<bool STORE>
__global__ __launch_bounds__(256) void k_gemm(const float* __restrict__ ctx,
                                              const bf16*  __restrict__ WcT2,
                                              const float* __restrict__ qb,
                                              const float* __restrict__ W2,
                                              float* __restrict__ score,
                                              bf16* __restrict__ ctxb) {
    __shared__ char smem[73728];
    bf16* As = (bf16*)smem;                 // [2][64*32]   8 KB
    bf16* Bs = (bf16*)(smem + 8192);        // [2][512*32] 64 KB
    float* red = (float*)smem;              // epilogue overlay on As

    const int tid  = threadIdx.x;
    const int mblk = blockIdx.x;            // 0..1023
    const size_t row_base = (size_t)mblk * BM;
    const int b = mblk >> 5;                // 32 mblks per batch

    const int lane = tid & 63;
    const int wn   = tid >> 6;              // 0..3 (x128 cols)
    const int l16  = lane & 15;
    const int quad = lane >> 4;

    f32x4 acc[4][8] = {};

    const int am = tid >> 2;                // 0..63
    const int ak = (tid & 3) << 3;          // 0,8,16,24
    const float* actx = ctx + (row_base + am) * (size_t)DC + ak;
    bf16* actxb = STORE ? (ctxb + (row_base + am) * (size_t)DC + ak) : (bf16*)nullptr;
    const int aoff = tid * 8;               // == am*32+ak
    const bf16* bsrc = WcT2 + tid * 8;
    const int boff = tid * 8;
    const int fA = l16 * BK + quad * 8;
    const int fB = (wn * 128 + l16) * BK + quad * 8;

    // ---- prologue: stage k-step 0 into buffer 0 ----
    {
        const float4 v0 = *(const float4*)(actx);
        const float4 v1 = *(const float4*)(actx + 4);
        bf16x8 a8 = { (bf16)v0.x, (bf16)v0.y, (bf16)v0.z, (bf16)v0.w,
                      (bf16)v1.x, (bf16)v1.y, (bf16)v1.z, (bf16)v1.w };
        *(bf16x8*)(As + aoff) = a8;
        if (STORE) *(bf16x8*)actxb = a8;
        #pragma unroll
        for (int i = 0; i < 8; ++i)
            GLD16(bsrc + i * 2048, Bs + boff + i * 2048);
    }
    __syncthreads();

    for (int kb = 0; kb < DC / BK; ++kb) {
        const int cur = kb & 1, nxt = cur ^ 1;
        float4 av0, av1;
        if (kb < 31) {
            #pragma unroll
            for (int i = 0; i < 8; ++i)
                GLD16(bsrc + (size_t)(kb + 1) * 16384 + i * 2048,
                      Bs + nxt * 16384 + boff + i * 2048);
            av0 = *(const float4*)(actx + (kb + 1) * BK);
            av1 = *(const float4*)(actx + (kb + 1) * BK + 4);
        }

        bf16x8 aF[4], bF[8];
        const bf16* aP = As + cur * 2048 + fA;
        const bf16* bP = Bs + cur * 16384 + fB;
        #pragma unroll
        for (int mf = 0; mf < 4; ++mf) aF[mf] = *(const bf16x8*)(aP + mf * (16 * BK));
        #pragma unroll
        for (int nf = 0; nf < 8; ++nf) bF[nf] = *(const bf16x8*)(bP + nf * (16 * BK));
        #pragma unroll
        for (int mf = 0; mf < 4; ++mf)
            #pragma unroll
            for (int nf = 0; nf < 8; ++nf)
                acc[mf][nf] = __builtin_amdgcn_mfma_f32_16x16x32_bf16(aF[mf], bF[nf], acc[mf][nf], 0, 0, 0);

        if (kb < 31) {
            bf16x8 a8 = { (bf16)av0.x, (bf16)av0.y, (bf16)av0.z, (bf16)av0.w,
                          (bf16)av1.x, (bf16)av1.y, (bf16)av1.z, (bf16)av1.w };
            *(bf16x8*)(As + nxt * 2048 + aoff) = a8;
            if (STORE) *(bf16x8*)(actxb + (kb + 1) * BK) = a8;
        }
        __syncthreads();
    }

    // ---- epilogue: s(row) = sum over this wave's 128 cols of tanh(acc+qb)*w2 ----
    float qv[8], wv[8];
    #pragma unroll
    for (int nf = 0; nf < 8; ++nf) {
        int c = wn * 128 + nf * 16 + l16;
        qv[nf] = qb[(size_t)b * H_ + c];
        wv[nf] = W2[c];
    }
    #pragma unroll
    for (int mf = 0; mf < 4; ++mf) {
        #pragma unroll
        for (int r = 0; r < 4; ++r) {
            float s = 0.0f;
            #pragma unroll
            for (int nf = 0; nf < 8; ++nf) {
                float x = acc[mf][nf][r] + qv[nf];
                float t = 1.0f - 2.0f / (1.0f + __expf(2.0f * x)); // tanh, saturates
                s = fmaf(t, wv[nf], s);
            }
            s += __shfl_xor(s, 1);
            s += __shfl_xor(s, 2);
            s += __shfl_xor(s, 4);
            s += __shfl_xor(s, 8);
            if (l16 == 0)
                red[(mf * 16 + quad * 4 + r) * 4 + wn] = s;
        }
    }
    __syncthreads();
    if (tid < BM)
        score[row_base + tid] = red[tid * 4] + red[tid * 4 + 1] + red[tid * 4 + 2] + red[tid * 4 + 3];
}

// ---------- Fused softmax + expected_ctx (+ p_ctx write) ----------
// grid (8 hblk, 32 b), 256 thr. Each block recomputes the row softmax
// (deterministic, identical across hblk) and produces 128 output cols.
template<bool BF>
__global__ __launch_bounds__(256) void k_exp(const float* __restrict__ score,
                                             const float* __restrict__ b2p,
                                             const int*   __restrict__ mask,
                                             const float* __restrict__ ctxf,
                                             const bf16*  __restrict__ ctxb,
                                             float* __restrict__ expected,
                                             float* __restrict__ p_out) {
    const int hblk = blockIdx.x, b = blockIdx.y, tid = threadIdx.x;
    __shared__ float ps[S_];               // un-normalized exp weights, 8 KB
    __shared__ float red[256];
    __shared__ float red2[8 * 32 * 4];     // 4 KB

    const float b2 = b2p[0];
    float loc[8];
    float mx = -1e30f;
    #pragma unroll
    for (int i = 0; i < 8; ++i) {
        size_t r = (size_t)b * S_ + i * 256 + tid;
        float v = score[r] + b2;
        if (mask[r] == 0) v = -10000.0f;
        loc[i] = v;
        mx = fmaxf(mx, v);
    }
    red[tid] = mx; __syncthreads();
    for (int o = 128; o > 0; o >>= 1) {
        if (tid < o) red[tid] = fmaxf(red[tid], red[tid + o]);
        __syncthreads();
    }
    mx = red[0]; __syncthreads();
    float se = 0.0f;
    #pragma unroll
    for (int i = 0; i < 8; ++i) {
        float e = __expf(loc[i] - mx);
        ps[i * 256 + tid] = e;
        se += e;
    }
    red[tid] = se; __syncthreads();
    for (int o = 128; o > 0; o >>= 1) {
        if (tid < o) red[tid] += red[tid + o];
        __syncthreads();
    }
    const float inv = 1.0f / red[0];
    __syncthreads();
    if (hblk == 0) {
        #pragma unroll
        for (int i = 0; i < 8; ++i)
            p_out[(size_t)b * S_ + i * 256 + tid] = ps[i * 256 + tid] * inv;
    }

    // weighted ctx sum over all 2048 rows for cols [hblk*128, +128)
    const int c4  = (tid & 31) * 4;
    const int rg  = tid >> 5;              // 0..7 row-group
    const int col0 = hblk * 128;
    float a0 = 0.f, a1 = 0.f, a2 = 0.f, a3 = 0.f;
    if (BF) {
        const bf16* base = ctxb + ((size_t)b * S_ + rg) * DC + col0 + c4;
        #pragma unroll 4
        for (int s0 = 0; s0 < S_; s0 += 8) {
            float w = ps[s0 + rg];
            bf16x4 v = *(const bf16x4*)(base + (size_t)s0 * DC);
            a0 = fmaf(w, (float)v[0], a0);
            a1 = fmaf(w, (float)v[1], a1);
            a2 = fmaf(w, (float)v[2], a2);
            a3 = fmaf(w, (float)v[3], a3);
        }
    } else {
        const float* base = ctxf + ((size_t)b * S_ + rg) * DC + col0 + c4;
        #pragma unroll 4
        for (int s0 = 0; s0 < S_; s0 += 8) {
            float w = ps[s0 + rg];
            const float4 v = *(const float4*)(base + (size_t)s0 * DC);
            a0 = fmaf(w, v.x, a0);
            a1 = fmaf(w, v.y, a1);
            a2 = fmaf(w, v.z, a2);
            a3 = fmaf(w, v.w, a3);
        }
    }
    float* r2 = &red2[(rg * 32 + (tid & 31)) * 4];
    r2[0] = a0; r2[1] = a1; r2[2] = a2; r2[3] = a3;
    __syncthreads();
    if (tid < 32) {
        float s0 = 0.f, s1 = 0.f, s2 = 0.f, s3 = 0.f;
        #pragma unroll
        for (int g = 0; g < 8; ++g) {
            const float* q = &red2[(g * 32 + tid) * 4];
            s0 += q[0]; s1 += q[1]; s2 += q[2]; s3 += q[3];
        }
        float4 o = { s0 * inv, s1 * inv, s2 * inv, s3 * inv };
        *(float4*)(expected + (size_t)b * DC + col0 + tid * 4) = o;
    }
}

extern "C" void kernel_launch(void* const* d_in, const int* in_sizes, int n_in,
                              void* d_out, int out_size, void* d_ws, size_t ws_size,
                              hipStream_t stream) {
    (void)in_sizes; (void)n_in; (void)out_size;
    const float* ctx   = (const float*)d_in[0];
    const float* query = (const float*)d_in[1];
    const float* W1    = (const float*)d_in[2];
    const float* b1    = (const float*)d_in[3];
    const float* W2    = (const float*)d_in[4];
    const float* b2    = (const float*)d_in[5];
    const int*   mask  = (const int*)d_in[6];

    float* out      = (float*)d_out;
    float* expected = out;                 // 32*1024
    float* p_out    = out + 32768;         // 32*2048

    const size_t CTXB_BYTES = (size_t)M_ * DC * sizeof(bf16);     // 128 MB
    const size_t need = CTXB_BYTES + (1 << 20) + (64 << 10) + (256 << 10) + 256;
    char* w = (char*)d_ws;

    if (ws_size >= need) {
        bf16*  ctxb  = (bf16*)w;
        bf16*  WcT2  = (bf16*)(w + CTXB_BYTES);
        float* qb    = (float*)(w + CTXB_BYTES + (1 << 20));
        float* score = (float*)(w + CTXB_BYTES + (1 << 20) + (64 << 10));
        k_prep      <<<512, 256, 0, stream>>>(W1, query, b1, WcT2, qb);
        k_gemm<true><<<M_ / BM, 256, 0, stream>>>(ctx, WcT2, qb, W2, score, ctxb);
        k_exp<true> <<<dim3(8, B_), 256, 0, stream>>>(score, b2, mask, ctx, ctxb, expected, p_out);
    } else {
        bf16*  WcT2  = (bf16*)w;
        float* qb    = (float*)(w + (1 << 20));
        float* score = (float*)(w + (1 << 20) + (64 << 10));
        k_prep       <<<512, 256, 0, stream>>>(W1, query, b1, WcT2, qb);
        k_gemm<false><<<M_ / BM, 256, 0, stream>>>(ctx, WcT2, qb, W2, score, nullptr);
        k_exp<false> <<<dim3(8, B_), 256, 0, stream>>>(score, b2, mask, ctx, nullptr, expected, p_out);
    }
}